// Round 10
// baseline (175.116 us; speedup 1.0000x reference)
//
#include <hip/hip_runtime.h>
#include <math.h>

#define NN 4
#define CCH 128
#define HH 96
#define WW 96
#define SS (HH*WW)          // 9216
#define GG 4
#define GC 32
#define PP 9
#define NPIX (NN*HH*WW)     // 36864

typedef short bf16x8 __attribute__((ext_vector_type(8)));
typedef float f32x4 __attribute__((ext_vector_type(4)));
typedef unsigned short u16;
typedef unsigned int u32;

static __device__ __forceinline__ u16 f2bf(float f) {
  unsigned u = __builtin_bit_cast(unsigned, f);
  unsigned r = (u + 0x7fffu + ((u >> 16) & 1u)) >> 16;  // RNE
  return (u16)r;
}
static __device__ __forceinline__ float bflo(u32 u) {
  return __builtin_bit_cast(float, u << 16);
}
static __device__ __forceinline__ float bfhi(u32 u) {
  return __builtin_bit_cast(float, u & 0xffff0000u);
}

// ---------------- prep: transpose + bf16-convert weights (+ dw conv weights)
__global__ __launch_bounds__(128) void k_prep(const float* __restrict__ w_in,
    const float* __restrict__ w_off, const float* __restrict__ w_mask,
    const float* __restrict__ w_out, const float* __restrict__ dw_w,
    u16* __restrict__ w_inT, u16* __restrict__ w_omT, u16* __restrict__ w_outT,
    u16* __restrict__ dw_wT) {
  int r = blockIdx.x, k = threadIdx.x;
  if (r < 128) {
    w_inT[r*128 + k] = f2bf(w_in[k*128 + r]);
  } else if (r < 240) {
    int c = r - 128;
    float v = 0.f;
    if (c < 72) v = w_off[k*72 + c];
    else if (c < 108) v = w_mask[k*36 + (c - 72)];
    w_omT[c*128 + k] = f2bf(v);
  } else if (r < 368) {
    int c = r - 240;
    w_outT[c*128 + k] = f2bf(w_out[k*128 + c]);
  } else {
    int j = r - 368;                      // 0..8
    dw_wT[j*128 + k] = f2bf(dw_w[k*9 + j]);
  }
}

// ---------------- fused transpose + input projection (64 px/block, 512 thr)
__global__ __launch_bounds__(512) void k_trproj(const float* __restrict__ x,
    const u16* __restrict__ wT, const float* __restrict__ bias,
    u16* __restrict__ xTb, u16* __restrict__ xpb) {
  __shared__ u16 tile[64][136];
  int t = threadIdx.x;
  int pb = blockIdx.x * 64;             // same n (9216%64==0)
  int n = pb / SS, ps = pb % SS;
  const float* src = x + ((size_t)n*CCH)*SS + ps;

  // ---- phase L: 128 c-rows x 16 float4 = 2048 tasks
  #pragma unroll
  for (int i = 0; i < 4; ++i) {
    int fid = t + i*512;
    int c = fid >> 4, q = fid & 15;
    float4 v = *(const float4*)(src + (size_t)c*SS + q*4);
    int px = q*4;
    tile[px+0][c] = f2bf(v.x);
    tile[px+1][c] = f2bf(v.y);
    tile[px+2][c] = f2bf(v.z);
    tile[px+3][c] = f2bf(v.w);
  }
  __syncthreads();

  // ---- phase M1: coalesced xTb store (64px x 64 u32 = 4096 tasks)
  {
    u32* dst = (u32*)(xTb + (size_t)pb*CCH);
    #pragma unroll
    for (int i = 0; i < 8; ++i) {
      int gidx = t + i*512;
      int px = gidx >> 6, cp = gidx & 63;
      dst[(size_t)px*64 + cp] = *(const u32*)&tile[px][cp*2];
    }
  }

  // ---- phase M2: MFMA proj. 8 waves = (px quarter 0..3) x (nt half 0..1)
  {
    int wv = t >> 6, l = t & 63, c16 = l & 15, kq = l >> 4;
    int pxl0 = (wv & 3) * 16;
    int nt0 = (wv >> 2) * 4;
    bf16x8 a[4];
    #pragma unroll
    for (int ks = 0; ks < 4; ++ks)
      a[ks] = *(const bf16x8*)&tile[pxl0 + c16][kq*8 + ks*32];
    f32x4 acc[4] = {};
    #pragma unroll
    for (int ks = 0; ks < 4; ++ks) {
      #pragma unroll
      for (int j = 0; j < 4; ++j) {
        bf16x8 b = *(const bf16x8*)(wT + (size_t)((nt0+j)*16 + c16)*CCH + ks*32 + kq*8);
        acc[j] = __builtin_amdgcn_mfma_f32_16x16x32_bf16(a[ks], b, acc[j], 0, 0, 0);
      }
    }
    #pragma unroll
    for (int j = 0; j < 4; ++j) {
      int c = (nt0+j)*16 + c16;
      float bs = bias[c];
      #pragma unroll
      for (int r = 0; r < 4; ++r)
        xpb[(size_t)(pb + pxl0 + kq*4 + r)*CCH + c] = f2bf(acc[j][r] + bs);
    }
  }
}

// ---------------- fused dwconv3x3 + LN + GELU + om heads (MFMA) + softmax
//                  32 px/block, 512 threads
__global__ __launch_bounds__(512) void k_dwom(const u16* __restrict__ xTb,
    const u16* __restrict__ dw_wT, const float* __restrict__ dw_b,
    const float* __restrict__ ln_g, const float* __restrict__ ln_b,
    const u16* __restrict__ wTom, const float* __restrict__ b_off,
    const float* __restrict__ b_mask,
    float* __restrict__ off, float* __restrict__ mask) {
  __shared__ u16 x1t[32][136];
  __shared__ float msk[32][40];
  int t = threadIdx.x;
  int blk = blockIdx.x;
  const int W32 = WW/32;                        // 3
  int w0 = (blk % W32) * 32;
  int h  = (blk / W32) % HH;
  int n  = blk / (W32*HH);
  size_t pix0 = (size_t)n*SS + (size_t)h*WW + w0;

  // ---- phase 1: conv + LN + GELU (thread = px(0..31) x 8-ch group)
  {
    int px = t >> 4, cg = t & 15;
    int w = w0 + px;
    int c0 = cg * 8;
    const u16* src = xTb + (size_t)n*SS*CCH + c0;
    float wtv[9][8];
    #pragma unroll
    for (int j = 0; j < 9; ++j) {
      bf16x8 wr = *(const bf16x8*)(dw_wT + j*CCH + c0);
      u32 uw[4]; *(bf16x8*)uw = wr;
      #pragma unroll
      for (int q = 0; q < 4; ++q) { wtv[j][2*q] = bflo(uw[q]); wtv[j][2*q+1] = bfhi(uw[q]); }
    }
    float s8[8] = {};
    #pragma unroll
    for (int kh = 0; kh < 3; ++kh) {
      int yy = h - 1 + kh;
      if (yy < 0 || yy >= HH) continue;
      #pragma unroll
      for (int kw = 0; kw < 3; ++kw) {
        int xx = w - 1 + kw;
        if (xx < 0 || xx >= WW) continue;
        bf16x8 raw = *(const bf16x8*)(src + (size_t)(yy*WW + xx)*CCH);
        u32 uw[4]; *(bf16x8*)uw = raw;
        #pragma unroll
        for (int q = 0; q < 4; ++q) {
          s8[2*q]   = fmaf(bflo(uw[q]), wtv[kh*3+kw][2*q],   s8[2*q]);
          s8[2*q+1] = fmaf(bfhi(uw[q]), wtv[kh*3+kw][2*q+1], s8[2*q+1]);
        }
      }
    }
    float4 db0 = *(const float4*)(dw_b + c0);
    float4 db1 = *(const float4*)(dw_b + c0 + 4);
    s8[0]+=db0.x; s8[1]+=db0.y; s8[2]+=db0.z; s8[3]+=db0.w;
    s8[4]+=db1.x; s8[5]+=db1.y; s8[6]+=db1.z; s8[7]+=db1.w;
    float s1 = 0.f, s2 = 0.f;
    #pragma unroll
    for (int j = 0; j < 8; ++j) { s1 += s8[j]; s2 += s8[j]*s8[j]; }
    #pragma unroll
    for (int m = 8; m >= 1; m >>= 1) {
      s1 += __shfl_xor(s1, m);
      s2 += __shfl_xor(s2, m);
    }
    float mean = s1 * (1.f/128.f);
    float var  = s2 * (1.f/128.f) - mean*mean;
    float rstd = rsqrtf(var + 1e-5f);
    float4 lg0 = *(const float4*)(ln_g + c0);
    float4 lg1 = *(const float4*)(ln_g + c0 + 4);
    float4 lb0 = *(const float4*)(ln_b + c0);
    float4 lb1 = *(const float4*)(ln_b + c0 + 4);
    float lg[8] = {lg0.x,lg0.y,lg0.z,lg0.w,lg1.x,lg1.y,lg1.z,lg1.w};
    float lb[8] = {lb0.x,lb0.y,lb0.z,lb0.w,lb1.x,lb1.y,lb1.z,lb1.w};
    u32 pk[4];
    #pragma unroll
    for (int q = 0; q < 4; ++q) {
      float v0 = (s8[2*q]   - mean) * rstd * lg[2*q]   + lb[2*q];
      float v1 = (s8[2*q+1] - mean) * rstd * lg[2*q+1] + lb[2*q+1];
      float g0 = 0.5f * v0 * (1.f + erff(v0 * 0.70710678f));
      float g1 = 0.5f * v1 * (1.f + erff(v1 * 0.70710678f));
      pk[q] = (u32)f2bf(g0) | ((u32)f2bf(g1) << 16);
    }
    *(bf16x8*)&x1t[px][c0] = *(bf16x8*)pk;
  }
  __syncthreads();

  // ---- phase 2: om heads MFMA. 8 waves = (px half) x (nt quarter: {q, q+4})
  {
    int wv = t >> 6, l = t & 63, c16 = l & 15, kq = l >> 4;
    int pxh = wv & 1;
    int q = wv >> 1;
    int ntn = (q == 3) ? 1 : 2;
    f32x4 acc[2] = {};
    #pragma unroll
    for (int ks = 0; ks < 4; ++ks) {
      bf16x8 a = *(const bf16x8*)&x1t[pxh*16 + c16][kq*8 + ks*32];
      #pragma unroll
      for (int j = 0; j < 2; ++j) {
        if (j < ntn) {
          int nt = q + j*4;
          bf16x8 b = *(const bf16x8*)(wTom + (size_t)(nt*16 + c16)*CCH + ks*32 + kq*8);
          acc[j] = __builtin_amdgcn_mfma_f32_16x16x32_bf16(a, b, acc[j], 0, 0, 0);
        }
      }
    }
    #pragma unroll
    for (int j = 0; j < 2; ++j) {
      if (j < ntn) {
        int nt = q + j*4;
        int c = nt*16 + c16;
        float bs = (c < 72) ? b_off[c] : ((c < 108) ? b_mask[c - 72] : 0.f);
        #pragma unroll
        for (int r = 0; r < 4; ++r) {
          int px = pxh*16 + kq*4 + r;
          float v = acc[j][r] + bs;
          if (c < 72) off[(pix0 + px)*72 + c] = v;
          else if (c < 108) msk[px][c - 72] = v;
        }
      }
    }
  }
  __syncthreads();

  // ---- phase 3: softmax (32 px x 4 groups = 128 tasks)
  if (t < 128) {
    int px = t >> 2, g = t & 3;
    float mx = -1e30f;
    #pragma unroll
    for (int q = 0; q < PP; ++q) mx = fmaxf(mx, msk[px][g*PP + q]);
    float e[PP]; float sum = 0.f;
    #pragma unroll
    for (int q = 0; q < PP; ++q) { e[q] = __expf(msk[px][g*PP + q] - mx); sum += e[q]; }
    float inv = 1.f / sum;
    #pragma unroll
    for (int q = 0; q < PP; ++q)
      mask[(pix0 + px)*36 + g*PP + q] = e[q] * inv;
  }
}

// ---------------- fused DCN sampling + out proj (MFMA) + BN + SiLU + NCHW
//                  32 px/block, 512 threads
__global__ __launch_bounds__(512) void k_dcnout(const u16* __restrict__ xpb,
    const float* __restrict__ off, const float* __restrict__ mask,
    const u16* __restrict__ wTout, const float* __restrict__ b_out,
    const float* __restrict__ bn_g, const float* __restrict__ bn_b,
    const float* __restrict__ bn_mean, const float* __restrict__ bn_var,
    float* __restrict__ y) {
  __shared__ float smem[32*132];        // offs[32][72]|ms[32][36] then fout[32][132]
  __shared__ u16 dtile[32][136];
  float (*offs)[72] = (float(*)[72])smem;
  float (*ms)[36]   = (float(*)[36])(smem + 32*72);
  int t = threadIdx.x;
  int pb = blockIdx.x * 32;
  int n = pb / SS, rem = pb % SS;
  {
    const float* po = off + (size_t)pb*72;
    #pragma unroll
    for (int i = 0; i < 5; ++i) {
      int idx = t + i*512;
      if (idx < 32*72) smem[idx] = po[idx];
    }
    const float* pm = mask + (size_t)pb*36;
    #pragma unroll
    for (int i = 0; i < 3; ++i) {
      int idx = t + i*512;
      if (idx < 32*36) smem[32*72 + idx] = pm[idx];
    }
  }
  __syncthreads();

  // ---- phase 1: bilinear sampling, 3-point batches (12 loads in flight)
  {
    int pxl = t >> 4, unit = t & 15;
    int g = unit >> 2, ch0 = unit * 8;
    int pix = pb + pxl;
    int w = pix % WW; int h = (pix / WW) % HH;
    const u16* basep = xpb + (size_t)n*SS*CCH + ch0;
    float a8[8] = {};
    #pragma unroll
    for (int bt = 0; bt < 3; ++bt) {
      bf16x8 raw[3][4];
      float wgt[3][4];
      #pragma unroll
      for (int q = 0; q < 3; ++q) {
        int p = bt*3 + q;
        float offx = offs[pxl][(g*PP + p)*2 + 0];
        float offy = offs[pxl][(g*PP + p)*2 + 1];
        float mval = ms[pxl][g*PP + p];
        float ix = (float)w + 1.0f + (float)(p / 3 - 1) + offx;
        float iy = (float)h + 1.0f + (float)(p % 3 - 1) + offy;
        float x0f = floorf(ix), y0f = floorf(iy);
        float wx1 = ix - x0f, wx0 = 1.f - wx1;
        float wy1 = iy - y0f, wy0 = 1.f - wy1;
        int x0i = (int)x0f, y0i = (int)y0f;
        int ox0 = x0i - 1, oy0 = y0i - 1;   // padded -> original coords
        int ox1 = x0i,     oy1 = y0i;
        bool y0ok = (oy0 >= 0) & (oy0 < HH), y1ok = (oy1 >= 0) & (oy1 < HH);
        bool x0ok = (ox0 >= 0) & (ox0 < WW), x1ok = (ox1 >= 0) & (ox1 < WW);
        int cy0 = min(max(oy0, 0), HH-1), cy1 = min(max(oy1, 0), HH-1);
        int cx0 = min(max(ox0, 0), WW-1), cx1 = min(max(ox1, 0), WW-1);
        wgt[q][0] = ((y0ok & x0ok) ? wy0*wx0 : 0.f) * mval;
        wgt[q][1] = ((y0ok & x1ok) ? wy0*wx1 : 0.f) * mval;
        wgt[q][2] = ((y1ok & x0ok) ? wy1*wx0 : 0.f) * mval;
        wgt[q][3] = ((y1ok & x1ok) ? wy1*wx1 : 0.f) * mval;
        raw[q][0] = *(const bf16x8*)(basep + (size_t)(cy0*WW + cx0)*CCH);
        raw[q][1] = *(const bf16x8*)(basep + (size_t)(cy0*WW + cx1)*CCH);
        raw[q][2] = *(const bf16x8*)(basep + (size_t)(cy1*WW + cx0)*CCH);
        raw[q][3] = *(const bf16x8*)(basep + (size_t)(cy1*WW + cx1)*CCH);
      }
      #pragma unroll
      for (int q = 0; q < 3; ++q) {
        #pragma unroll
        for (int corner = 0; corner < 4; ++corner) {
          u32 uw[4]; *(bf16x8*)uw = raw[q][corner];
          float wg = wgt[q][corner];
          #pragma unroll
          for (int j = 0; j < 4; ++j) {
            a8[2*j]   = fmaf(wg, bflo(uw[j]), a8[2*j]);
            a8[2*j+1] = fmaf(wg, bfhi(uw[j]), a8[2*j+1]);
          }
        }
      }
    }
    u32 pk[4];
    #pragma unroll
    for (int j = 0; j < 4; ++j)
      pk[j] = (u32)f2bf(a8[2*j]) | ((u32)f2bf(a8[2*j+1]) << 16);
    *(bf16x8*)&dtile[pxl][ch0] = *(bf16x8*)pk;
  }
  __syncthreads();

  // ---- phase 2: out proj MFMA. 8 waves = (px half) x (nt quarter: {q,q+4})
  {
    int wv = t >> 6, l = t & 63, c16 = l & 15, kq = l >> 4;
    int pxh = wv & 1;
    int qd = wv >> 1;
    f32x4 acc[2] = {};
    #pragma unroll
    for (int ks = 0; ks < 4; ++ks) {
      bf16x8 a = *(const bf16x8*)&dtile[pxh*16 + c16][kq*8 + ks*32];
      #pragma unroll
      for (int j = 0; j < 2; ++j) {
        int nt = qd + j*4;
        bf16x8 b = *(const bf16x8*)(wTout + (size_t)(nt*16 + c16)*CCH + ks*32 + kq*8);
        acc[j] = __builtin_amdgcn_mfma_f32_16x16x32_bf16(a, b, acc[j], 0, 0, 0);
      }
    }
    float (*fout)[132] = (float(*)[132])smem;   // offs/ms dead after phase 1
    #pragma unroll
    for (int j = 0; j < 2; ++j) {
      int c = (qd + j*4)*16 + c16;
      float sc = rsqrtf(bn_var[c] + 1e-5f) * bn_g[c];
      float sh = bn_b[c] - bn_mean[c] * sc;
      float bs = b_out[c];
      #pragma unroll
      for (int r = 0; r < 4; ++r) {
        int px = pxh*16 + kq*4 + r;
        float v = (acc[j][r] + bs) * sc + sh;
        float sig = 1.f / (1.f + __expf(-v));
        fout[px][c] = v * sig;
      }
    }
  }
  __syncthreads();

  // ---- phase 3: NCHW store (float4 along pixels; 128c x 8 groups = 1024 tasks)
  {
    float (*fout)[132] = (float(*)[132])smem;
    float* dst = y + ((size_t)n*CCH)*SS + rem;
    #pragma unroll
    for (int i = 0; i < 2; ++i) {
      int id = t + i*512;
      int c = id >> 3, p4 = (id & 7) * 4;
      float4 v = { fout[p4][c], fout[p4+1][c], fout[p4+2][c], fout[p4+3][c] };
      *(float4*)(dst + (size_t)c*SS + p4) = v;
    }
  }
}

extern "C" void kernel_launch(void* const* d_in, const int* in_sizes, int n_in,
                              void* d_out, int out_size, void* d_ws, size_t ws_size,
                              hipStream_t stream) {
  const float* x       = (const float*)d_in[0];
  const float* dw_w    = (const float*)d_in[1];
  const float* dw_b    = (const float*)d_in[2];
  const float* ln_g    = (const float*)d_in[3];
  const float* ln_b    = (const float*)d_in[4];
  const float* w_off   = (const float*)d_in[5];
  const float* b_off   = (const float*)d_in[6];
  const float* w_mask  = (const float*)d_in[7];
  const float* b_mask  = (const float*)d_in[8];
  const float* w_in    = (const float*)d_in[9];
  const float* b_in    = (const float*)d_in[10];
  const float* w_out   = (const float*)d_in[11];
  const float* b_out   = (const float*)d_in[12];
  const float* bn_g    = (const float*)d_in[13];
  const float* bn_b    = (const float*)d_in[14];
  const float* bn_mean = (const float*)d_in[15];
  const float* bn_var  = (const float*)d_in[16];
  float* y = (float*)d_out;

  u16*  xTb  = (u16*)d_ws;                        // NPIX*128 bf16
  u16*  xpb  = xTb + (size_t)NPIX*CCH;            // NPIX*128 bf16
  float* offb = (float*)(xpb + (size_t)NPIX*CCH); // NPIX*72 f32
  float* mb   = offb + (size_t)NPIX*72;           // NPIX*36 f32
  u16*  wbuf  = (u16*)(mb + (size_t)NPIX*36);
  u16*  w_inT  = wbuf;                            // 128*128
  u16*  w_omT  = w_inT + 128*128;                 // 112*128
  u16*  w_outT = w_omT + 112*128;                 // 128*128
  u16*  dw_wTb = w_outT + 128*128;                // 9*128

  k_prep<<<377, 128, 0, stream>>>(w_in, w_off, w_mask, w_out, dw_w,
                                  w_inT, w_omT, w_outT, dw_wTb);
  k_trproj<<<NPIX/64, 512, 0, stream>>>(x, w_inT, b_in, xTb, xpb);
  k_dwom<<<NPIX/32, 512, 0, stream>>>(xTb, dw_wTb, dw_b, ln_g, ln_b,
                                      w_omT, b_off, b_mask, offb, mb);
  k_dcnout<<<NPIX/32, 512, 0, stream>>>(xpb, offb, mb, w_outT, b_out,
                                        bn_g, bn_b, bn_mean, bn_var, y);
}

// Round 11
// 164.289 us; speedup vs baseline: 1.0659x; 1.0659x over previous
//
#include <hip/hip_runtime.h>
#include <math.h>

#define NN 4
#define CCH 128
#define HH 96
#define WW 96
#define SS (HH*WW)          // 9216
#define GG 4
#define GC 32
#define PP 9
#define NPIX (NN*HH*WW)     // 36864

typedef short bf16x8 __attribute__((ext_vector_type(8)));
typedef float f32x4 __attribute__((ext_vector_type(4)));
typedef unsigned short u16;
typedef unsigned int u32;

static __device__ __forceinline__ u16 f2bf(float f) {
  unsigned u = __builtin_bit_cast(unsigned, f);
  unsigned r = (u + 0x7fffu + ((u >> 16) & 1u)) >> 16;  // RNE
  return (u16)r;
}
static __device__ __forceinline__ float bflo(u32 u) {
  return __builtin_bit_cast(float, u << 16);
}
static __device__ __forceinline__ float bfhi(u32 u) {
  return __builtin_bit_cast(float, u & 0xffff0000u);
}

// ---------------- prep: transpose + bf16-convert weights (+ dw conv weights)
__global__ __launch_bounds__(128) void k_prep(const float* __restrict__ w_in,
    const float* __restrict__ w_off, const float* __restrict__ w_mask,
    const float* __restrict__ w_out, const float* __restrict__ dw_w,
    u16* __restrict__ w_inT, u16* __restrict__ w_omT, u16* __restrict__ w_outT,
    u16* __restrict__ dw_wT) {
  int r = blockIdx.x, k = threadIdx.x;
  if (r < 128) {
    w_inT[r*128 + k] = f2bf(w_in[k*128 + r]);
  } else if (r < 240) {
    int c = r - 128;
    float v = 0.f;
    if (c < 72) v = w_off[k*72 + c];
    else if (c < 108) v = w_mask[k*36 + (c - 72)];
    w_omT[c*128 + k] = f2bf(v);
  } else if (r < 368) {
    int c = r - 240;
    w_outT[c*128 + k] = f2bf(w_out[k*128 + c]);
  } else {
    int j = r - 368;                      // 0..8
    dw_wT[j*128 + k] = f2bf(dw_w[k*9 + j]);
  }
}

// ---------------- fused transpose + input projection (32 px/block, 256 thr)
__global__ __launch_bounds__(256) void k_trproj(const float* __restrict__ x,
    const u16* __restrict__ wT, const float* __restrict__ bias,
    u16* __restrict__ xTb, u16* __restrict__ xpb) {
  __shared__ u16 tile[32][136];
  int t = threadIdx.x;
  int pb = blockIdx.x * 32;             // same n (9216%32==0)
  int n = pb / SS, ps = pb % SS;
  const float* src = x + ((size_t)n*CCH)*SS + ps;

  // ---- phase L: 128 c-rows x 8 float4 = 1024 tasks
  #pragma unroll
  for (int i = 0; i < 4; ++i) {
    int fid = t + i*256;
    int c = fid >> 3, q = fid & 7;
    float4 v = *(const float4*)(src + (size_t)c*SS + q*4);
    int px = q*4;
    tile[px+0][c] = f2bf(v.x);
    tile[px+1][c] = f2bf(v.y);
    tile[px+2][c] = f2bf(v.z);
    tile[px+3][c] = f2bf(v.w);
  }
  __syncthreads();

  // ---- phase M1: coalesced xTb store (32px x 64 u32 = 2048 tasks)
  {
    u32* dst = (u32*)(xTb + (size_t)pb*CCH);
    #pragma unroll
    for (int i = 0; i < 8; ++i) {
      int gidx = t + i*256;
      int px = gidx >> 6, cp = gidx & 63;
      dst[(size_t)px*64 + cp] = *(const u32*)&tile[px][cp*2];
    }
  }

  // ---- phase M2: MFMA proj. wave w: px half (w&1)*16, nt quarter (w>>1)*4
  {
    int wv = t >> 6, l = t & 63, c16 = l & 15, kq = l >> 4;
    int pxl0 = (wv & 1) * 16;
    int nt0 = (wv >> 1) * 4;
    bf16x8 a[4];
    #pragma unroll
    for (int ks = 0; ks < 4; ++ks)
      a[ks] = *(const bf16x8*)&tile[pxl0 + c16][kq*8 + ks*32];
    f32x4 acc[4] = {};
    #pragma unroll
    for (int ks = 0; ks < 4; ++ks) {
      #pragma unroll
      for (int j = 0; j < 4; ++j) {
        bf16x8 b = *(const bf16x8*)(wT + (size_t)((nt0+j)*16 + c16)*CCH + ks*32 + kq*8);
        acc[j] = __builtin_amdgcn_mfma_f32_16x16x32_bf16(a[ks], b, acc[j], 0, 0, 0);
      }
    }
    #pragma unroll
    for (int j = 0; j < 4; ++j) {
      int c = (nt0+j)*16 + c16;
      float bs = bias[c];
      #pragma unroll
      for (int r = 0; r < 4; ++r)
        xpb[(size_t)(pb + pxl0 + kq*4 + r)*CCH + c] = f2bf(acc[j][r] + bs);
    }
  }
}

// ---------------- MEGA: dwconv3x3+LN+GELU -> om heads (MFMA) -> softmax
//                  -> DCN sampling -> out proj (MFMA) -> BN+SiLU -> NCHW
//                  16 px/block (one row segment), 256 threads, 5 barriers.
//                  Offsets & masks never touch HBM.
__global__ __launch_bounds__(256) void k_dwomdcn(const u16* __restrict__ xTb,
    const u16* __restrict__ xpb,
    const u16* __restrict__ dw_wT, const float* __restrict__ dw_b,
    const float* __restrict__ ln_g, const float* __restrict__ ln_b,
    const u16* __restrict__ wTom, const float* __restrict__ b_off,
    const float* __restrict__ b_mask,
    const u16* __restrict__ wTout, const float* __restrict__ b_out,
    const float* __restrict__ bn_g, const float* __restrict__ bn_b,
    const float* __restrict__ bn_mean, const float* __restrict__ bn_var,
    float* __restrict__ y) {
  __shared__ u16 x1t[16][136];       // GELU(LN(conv)) bf16
  __shared__ u16 dtile[16][136];     // dcn result bf16
  __shared__ float fbuf[16][132];    // cols 0..71 offs, 72..107 mask; later fout
  int t = threadIdx.x;
  int blk = blockIdx.x;
  const int W16 = WW/16;                        // 6
  int w0 = (blk % W16) * 16;
  int h  = (blk / W16) % HH;
  int n  = blk / (W16*HH);
  size_t pix0 = (size_t)n*SS + (size_t)h*WW + w0;

  // ---- phase 1: conv + LN + GELU (thread = px(0..15) x 8-ch group)
  {
    int px = t >> 4, cg = t & 15;
    int w = w0 + px;
    int c0 = cg * 8;
    const u16* src = xTb + (size_t)n*SS*CCH + c0;
    float wtv[9][8];
    #pragma unroll
    for (int j = 0; j < 9; ++j) {
      bf16x8 wr = *(const bf16x8*)(dw_wT + j*CCH + c0);
      u32 uw[4]; *(bf16x8*)uw = wr;
      #pragma unroll
      for (int q = 0; q < 4; ++q) { wtv[j][2*q] = bflo(uw[q]); wtv[j][2*q+1] = bfhi(uw[q]); }
    }
    float s8[8] = {};
    #pragma unroll
    for (int kh = 0; kh < 3; ++kh) {
      int yy = h - 1 + kh;
      if (yy < 0 || yy >= HH) continue;
      #pragma unroll
      for (int kw = 0; kw < 3; ++kw) {
        int xx = w - 1 + kw;
        if (xx < 0 || xx >= WW) continue;
        bf16x8 raw = *(const bf16x8*)(src + (size_t)(yy*WW + xx)*CCH);
        u32 uw[4]; *(bf16x8*)uw = raw;
        #pragma unroll
        for (int q = 0; q < 4; ++q) {
          s8[2*q]   = fmaf(bflo(uw[q]), wtv[kh*3+kw][2*q],   s8[2*q]);
          s8[2*q+1] = fmaf(bfhi(uw[q]), wtv[kh*3+kw][2*q+1], s8[2*q+1]);
        }
      }
    }
    float4 db0 = *(const float4*)(dw_b + c0);
    float4 db1 = *(const float4*)(dw_b + c0 + 4);
    s8[0]+=db0.x; s8[1]+=db0.y; s8[2]+=db0.z; s8[3]+=db0.w;
    s8[4]+=db1.x; s8[5]+=db1.y; s8[6]+=db1.z; s8[7]+=db1.w;
    float s1 = 0.f, s2 = 0.f;
    #pragma unroll
    for (int j = 0; j < 8; ++j) { s1 += s8[j]; s2 += s8[j]*s8[j]; }
    #pragma unroll
    for (int m = 8; m >= 1; m >>= 1) {
      s1 += __shfl_xor(s1, m);
      s2 += __shfl_xor(s2, m);
    }
    float mean = s1 * (1.f/128.f);
    float var  = s2 * (1.f/128.f) - mean*mean;
    float rstd = rsqrtf(var + 1e-5f);
    float4 lg0 = *(const float4*)(ln_g + c0);
    float4 lg1 = *(const float4*)(ln_g + c0 + 4);
    float4 lb0 = *(const float4*)(ln_b + c0);
    float4 lb1 = *(const float4*)(ln_b + c0 + 4);
    float lg[8] = {lg0.x,lg0.y,lg0.z,lg0.w,lg1.x,lg1.y,lg1.z,lg1.w};
    float lb[8] = {lb0.x,lb0.y,lb0.z,lb0.w,lb1.x,lb1.y,lb1.z,lb1.w};
    u32 pk[4];
    #pragma unroll
    for (int q = 0; q < 4; ++q) {
      float v0 = (s8[2*q]   - mean) * rstd * lg[2*q]   + lb[2*q];
      float v1 = (s8[2*q+1] - mean) * rstd * lg[2*q+1] + lb[2*q+1];
      float g0 = 0.5f * v0 * (1.f + erff(v0 * 0.70710678f));
      float g1 = 0.5f * v1 * (1.f + erff(v1 * 0.70710678f));
      pk[q] = (u32)f2bf(g0) | ((u32)f2bf(g1) << 16);
    }
    *(bf16x8*)&x1t[px][c0] = *(bf16x8*)pk;
  }
  __syncthreads();

  // ---- phase 2: om heads via MFMA -> fbuf LDS (never HBM)
  {
    int wv = t >> 6, l = t & 63, c16 = l & 15, kq = l >> 4;
    int nt0 = wv*2;
    int ntn = (wv == 3) ? 1 : 2;
    f32x4 acc[2] = {};
    #pragma unroll
    for (int ks = 0; ks < 4; ++ks) {
      bf16x8 a = *(const bf16x8*)&x1t[c16][kq*8 + ks*32];
      #pragma unroll
      for (int j = 0; j < 2; ++j) {
        if (j < ntn) {
          bf16x8 b = *(const bf16x8*)(wTom + (size_t)((nt0+j)*16 + c16)*CCH + ks*32 + kq*8);
          acc[j] = __builtin_amdgcn_mfma_f32_16x16x32_bf16(a, b, acc[j], 0, 0, 0);
        }
      }
    }
    #pragma unroll
    for (int j = 0; j < 2; ++j) {
      if (j < ntn) {
        int c = (nt0+j)*16 + c16;
        float bs = (c < 72) ? b_off[c] : ((c < 108) ? b_mask[c - 72] : 0.f);
        #pragma unroll
        for (int r = 0; r < 4; ++r) {
          int px = kq*4 + r;
          if (c < 108) fbuf[px][c] = acc[j][r] + bs;
        }
      }
    }
  }
  __syncthreads();

  // ---- phase 3: softmax over mask logits (16 px x 4 groups = 64 tasks), in place
  if (t < 64) {
    int px = t >> 2, g = t & 3;
    float mx = -1e30f;
    #pragma unroll
    for (int q = 0; q < PP; ++q) mx = fmaxf(mx, fbuf[px][72 + g*PP + q]);
    float e[PP]; float sum = 0.f;
    #pragma unroll
    for (int q = 0; q < PP; ++q) { e[q] = __expf(fbuf[px][72 + g*PP + q] - mx); sum += e[q]; }
    float inv = 1.f / sum;
    #pragma unroll
    for (int q = 0; q < PP; ++q) fbuf[px][72 + g*PP + q] = e[q] * inv;
  }
  __syncthreads();

  // ---- phase 4: bilinear sampling, 3-point batches (12 loads in flight)
  {
    int pxl = t >> 4, unit = t & 15;
    int g = unit >> 2, ch0 = unit * 8;
    int w = w0 + pxl;
    const u16* basep = xpb + (size_t)n*SS*CCH + ch0;
    float a8[8] = {};
    #pragma unroll
    for (int bt = 0; bt < 3; ++bt) {
      bf16x8 raw[3][4];
      float wgt[3][4];
      #pragma unroll
      for (int q = 0; q < 3; ++q) {
        int p = bt*3 + q;
        float offx = fbuf[pxl][(g*PP + p)*2 + 0];
        float offy = fbuf[pxl][(g*PP + p)*2 + 1];
        float mval = fbuf[pxl][72 + g*PP + p];
        float ix = (float)w + 1.0f + (float)(p / 3 - 1) + offx;
        float iy = (float)h + 1.0f + (float)(p % 3 - 1) + offy;
        float x0f = floorf(ix), y0f = floorf(iy);
        float wx1 = ix - x0f, wx0 = 1.f - wx1;
        float wy1 = iy - y0f, wy0 = 1.f - wy1;
        int x0i = (int)x0f, y0i = (int)y0f;
        int ox0 = x0i - 1, oy0 = y0i - 1;   // padded -> original coords
        int ox1 = x0i,     oy1 = y0i;
        bool y0ok = (oy0 >= 0) & (oy0 < HH), y1ok = (oy1 >= 0) & (oy1 < HH);
        bool x0ok = (ox0 >= 0) & (ox0 < WW), x1ok = (ox1 >= 0) & (ox1 < WW);
        int cy0 = min(max(oy0, 0), HH-1), cy1 = min(max(oy1, 0), HH-1);
        int cx0 = min(max(ox0, 0), WW-1), cx1 = min(max(ox1, 0), WW-1);
        wgt[q][0] = ((y0ok & x0ok) ? wy0*wx0 : 0.f) * mval;
        wgt[q][1] = ((y0ok & x1ok) ? wy0*wx1 : 0.f) * mval;
        wgt[q][2] = ((y1ok & x0ok) ? wy1*wx0 : 0.f) * mval;
        wgt[q][3] = ((y1ok & x1ok) ? wy1*wx1 : 0.f) * mval;
        raw[q][0] = *(const bf16x8*)(basep + (size_t)(cy0*WW + cx0)*CCH);
        raw[q][1] = *(const bf16x8*)(basep + (size_t)(cy0*WW + cx1)*CCH);
        raw[q][2] = *(const bf16x8*)(basep + (size_t)(cy1*WW + cx0)*CCH);
        raw[q][3] = *(const bf16x8*)(basep + (size_t)(cy1*WW + cx1)*CCH);
      }
      #pragma unroll
      for (int q = 0; q < 3; ++q) {
        #pragma unroll
        for (int corner = 0; corner < 4; ++corner) {
          u32 uw[4]; *(bf16x8*)uw = raw[q][corner];
          float wg = wgt[q][corner];
          #pragma unroll
          for (int j = 0; j < 4; ++j) {
            a8[2*j]   = fmaf(wg, bflo(uw[j]), a8[2*j]);
            a8[2*j+1] = fmaf(wg, bfhi(uw[j]), a8[2*j+1]);
          }
        }
      }
    }
    u32 pk[4];
    #pragma unroll
    for (int j = 0; j < 4; ++j)
      pk[j] = (u32)f2bf(a8[2*j]) | ((u32)f2bf(a8[2*j+1]) << 16);
    *(bf16x8*)&dtile[pxl][ch0] = *(bf16x8*)pk;
  }
  __syncthreads();   // dtile ready; fbuf dead -> reusable as fout

  // ---- phase 5: out proj MFMA + BN + SiLU -> fbuf (as fout)
  {
    int wv = t >> 6, l = t & 63, c16 = l & 15, kq = l >> 4;
    f32x4 acc[2] = {};
    #pragma unroll
    for (int ks = 0; ks < 4; ++ks) {
      bf16x8 a = *(const bf16x8*)&dtile[c16][kq*8 + ks*32];
      #pragma unroll
      for (int j = 0; j < 2; ++j) {
        int nt = wv*2 + j;
        bf16x8 b = *(const bf16x8*)(wTout + (size_t)(nt*16 + c16)*CCH + ks*32 + kq*8);
        acc[j] = __builtin_amdgcn_mfma_f32_16x16x32_bf16(a, b, acc[j], 0, 0, 0);
      }
    }
    #pragma unroll
    for (int j = 0; j < 2; ++j) {
      int c = (wv*2 + j)*16 + c16;
      float sc = rsqrtf(bn_var[c] + 1e-5f) * bn_g[c];
      float sh = bn_b[c] - bn_mean[c] * sc;
      float bs = b_out[c];
      #pragma unroll
      for (int r = 0; r < 4; ++r) {
        int px = kq*4 + r;
        float v = (acc[j][r] + bs) * sc + sh;
        float sig = 1.f / (1.f + __expf(-v));
        fbuf[px][c] = v * sig;
      }
    }
  }
  __syncthreads();

  // ---- phase 6: NCHW store (float4 along pixels; 128c x 4 quads = 512 tasks)
  {
    float* dst = y + ((size_t)n*CCH)*SS + (size_t)h*WW + w0;
    #pragma unroll
    for (int i = 0; i < 2; ++i) {
      int id = t + i*256;
      int c = id >> 2, p4 = (id & 3) * 4;
      float4 v = { fbuf[p4][c], fbuf[p4+1][c], fbuf[p4+2][c], fbuf[p4+3][c] };
      *(float4*)(dst + (size_t)c*SS + p4) = v;
    }
  }
}

extern "C" void kernel_launch(void* const* d_in, const int* in_sizes, int n_in,
                              void* d_out, int out_size, void* d_ws, size_t ws_size,
                              hipStream_t stream) {
  const float* x       = (const float*)d_in[0];
  const float* dw_w    = (const float*)d_in[1];
  const float* dw_b    = (const float*)d_in[2];
  const float* ln_g    = (const float*)d_in[3];
  const float* ln_b    = (const float*)d_in[4];
  const float* w_off   = (const float*)d_in[5];
  const float* b_off   = (const float*)d_in[6];
  const float* w_mask  = (const float*)d_in[7];
  const float* b_mask  = (const float*)d_in[8];
  const float* w_in    = (const float*)d_in[9];
  const float* b_in    = (const float*)d_in[10];
  const float* w_out   = (const float*)d_in[11];
  const float* b_out   = (const float*)d_in[12];
  const float* bn_g    = (const float*)d_in[13];
  const float* bn_b    = (const float*)d_in[14];
  const float* bn_mean = (const float*)d_in[15];
  const float* bn_var  = (const float*)d_in[16];
  float* y = (float*)d_out;

  u16*  xTb  = (u16*)d_ws;                        // NPIX*128 bf16
  u16*  xpb  = xTb + (size_t)NPIX*CCH;            // NPIX*128 bf16
  u16*  wbuf = xpb + (size_t)NPIX*CCH;
  u16*  w_inT  = wbuf;                            // 128*128
  u16*  w_omT  = w_inT + 128*128;                 // 112*128
  u16*  w_outT = w_omT + 112*128;                 // 128*128
  u16*  dw_wTb = w_outT + 128*128;                // 9*128

  k_prep<<<377, 128, 0, stream>>>(w_in, w_off, w_mask, w_out, dw_w,
                                  w_inT, w_omT, w_outT, dw_wTb);
  k_trproj<<<NPIX/32, 256, 0, stream>>>(x, w_inT, b_in, xTb, xpb);
  k_dwomdcn<<<NPIX/16, 256, 0, stream>>>(xTb, xpb, dw_wTb, dw_b, ln_g, ln_b,
                                         w_omT, b_off, b_mask,
                                         w_outT, b_out,
                                         bn_g, bn_b, bn_mean, bn_var, y);
}

// Round 12
// 161.401 us; speedup vs baseline: 1.0850x; 1.0179x over previous
//
#include <hip/hip_runtime.h>
#include <math.h>

#define NN 4
#define CCH 128
#define HH 96
#define WW 96
#define SS (HH*WW)          // 9216
#define GG 4
#define GC 32
#define PP 9
#define NPIX (NN*HH*WW)     // 36864

typedef short bf16x8 __attribute__((ext_vector_type(8)));
typedef float f32x4 __attribute__((ext_vector_type(4)));
typedef unsigned short u16;
typedef unsigned int u32;

static __device__ __forceinline__ u16 f2bf(float f) {
  unsigned u = __builtin_bit_cast(unsigned, f);
  unsigned r = (u + 0x7fffu + ((u >> 16) & 1u)) >> 16;  // RNE
  return (u16)r;
}
static __device__ __forceinline__ float bflo(u32 u) {
  return __builtin_bit_cast(float, u << 16);
}
static __device__ __forceinline__ float bfhi(u32 u) {
  return __builtin_bit_cast(float, u & 0xffff0000u);
}

// ---------------- prep: transpose + bf16-convert weights (+ dw conv weights)
__global__ __launch_bounds__(128) void k_prep(const float* __restrict__ w_in,
    const float* __restrict__ w_off, const float* __restrict__ w_mask,
    const float* __restrict__ w_out, const float* __restrict__ dw_w,
    u16* __restrict__ w_inT, u16* __restrict__ w_omT, u16* __restrict__ w_outT,
    u16* __restrict__ dw_wT) {
  int r = blockIdx.x, k = threadIdx.x;
  if (r < 128) {
    w_inT[r*128 + k] = f2bf(w_in[k*128 + r]);
  } else if (r < 240) {
    int c = r - 128;
    float v = 0.f;
    if (c < 72) v = w_off[k*72 + c];
    else if (c < 108) v = w_mask[k*36 + (c - 72)];
    w_omT[c*128 + k] = f2bf(v);
  } else if (r < 368) {
    int c = r - 240;
    w_outT[c*128 + k] = f2bf(w_out[k*128 + c]);
  } else {
    int j = r - 368;                      // 0..8
    dw_wT[j*128 + k] = f2bf(dw_w[k*9 + j]);
  }
}

// ---------------- fused transpose + input projection (32 px/block, 256 thr)
__global__ __launch_bounds__(256) void k_trproj(const float* __restrict__ x,
    const u16* __restrict__ wT, const float* __restrict__ bias,
    u16* __restrict__ xTb, u16* __restrict__ xpb) {
  __shared__ u16 tile[32][136];
  int t = threadIdx.x;
  int pb = blockIdx.x * 32;             // same n (9216%32==0)
  int n = pb / SS, ps = pb % SS;
  const float* src = x + ((size_t)n*CCH)*SS + ps;

  // ---- phase L: 128 c-rows x 8 float4 = 1024 tasks
  #pragma unroll
  for (int i = 0; i < 4; ++i) {
    int fid = t + i*256;
    int c = fid >> 3, q = fid & 7;
    float4 v = *(const float4*)(src + (size_t)c*SS + q*4);
    int px = q*4;
    tile[px+0][c] = f2bf(v.x);
    tile[px+1][c] = f2bf(v.y);
    tile[px+2][c] = f2bf(v.z);
    tile[px+3][c] = f2bf(v.w);
  }
  __syncthreads();

  // ---- phase M1: coalesced xTb store (32px x 64 u32 = 2048 tasks)
  {
    u32* dst = (u32*)(xTb + (size_t)pb*CCH);
    #pragma unroll
    for (int i = 0; i < 8; ++i) {
      int gidx = t + i*256;
      int px = gidx >> 6, cp = gidx & 63;
      dst[(size_t)px*64 + cp] = *(const u32*)&tile[px][cp*2];
    }
  }

  // ---- phase M2: MFMA proj. wave w: px half (w&1)*16, nt quarter (w>>1)*4
  {
    int wv = t >> 6, l = t & 63, c16 = l & 15, kq = l >> 4;
    int pxl0 = (wv & 1) * 16;
    int nt0 = (wv >> 1) * 4;
    bf16x8 a[4];
    #pragma unroll
    for (int ks = 0; ks < 4; ++ks)
      a[ks] = *(const bf16x8*)&tile[pxl0 + c16][kq*8 + ks*32];
    f32x4 acc[4] = {};
    #pragma unroll
    for (int ks = 0; ks < 4; ++ks) {
      #pragma unroll
      for (int j = 0; j < 4; ++j) {
        bf16x8 b = *(const bf16x8*)(wT + (size_t)((nt0+j)*16 + c16)*CCH + ks*32 + kq*8);
        acc[j] = __builtin_amdgcn_mfma_f32_16x16x32_bf16(a[ks], b, acc[j], 0, 0, 0);
      }
    }
    #pragma unroll
    for (int j = 0; j < 4; ++j) {
      int c = (nt0+j)*16 + c16;
      float bs = bias[c];
      #pragma unroll
      for (int r = 0; r < 4; ++r)
        xpb[(size_t)(pb + pxl0 + kq*4 + r)*CCH + c] = f2bf(acc[j][r] + bs);
    }
  }
}

// ---------------- MEGA: dwconv3x3+LN+GELU -> om heads (MFMA) -> softmax
//                  -> sample-precompute -> DCN sampling -> out proj (MFMA)
//                  -> BN+SiLU -> NCHW.  16 px/block, 256 threads, 7 barriers.
__global__ __launch_bounds__(256) void k_dwomdcn(const u16* __restrict__ xTb,
    const u16* __restrict__ xpb,
    const u16* __restrict__ dw_wT, const float* __restrict__ dw_b,
    const float* __restrict__ ln_g, const float* __restrict__ ln_b,
    const u16* __restrict__ wTom, const float* __restrict__ b_off,
    const float* __restrict__ b_mask,
    const u16* __restrict__ wTout, const float* __restrict__ b_out,
    const float* __restrict__ bn_g, const float* __restrict__ bn_b,
    const float* __restrict__ bn_mean, const float* __restrict__ bn_var,
    float* __restrict__ y) {
  __shared__ u16 x1t[16][136];       // GELU(LN(conv)) bf16
  __shared__ u16 dtile[16][136];     // dcn result bf16
  __shared__ float fbuf[16][132];    // cols 0..71 offs, 72..107 mask; later fout
  __shared__ float pinfo[16*GG*PP][6]; // per (px,g,p): idx01, idx23, w0..w3
  int t = threadIdx.x;
  int blk = blockIdx.x;
  const int W16 = WW/16;                        // 6
  int w0 = (blk % W16) * 16;
  int h  = (blk / W16) % HH;
  int n  = blk / (W16*HH);

  // ---- phase 1: conv + LN + GELU (thread = px(0..15) x 8-ch group)
  {
    int px = t >> 4, cg = t & 15;
    int w = w0 + px;
    int c0 = cg * 8;
    const u16* src = xTb + (size_t)n*SS*CCH + c0;
    float wtv[9][8];
    #pragma unroll
    for (int j = 0; j < 9; ++j) {
      bf16x8 wr = *(const bf16x8*)(dw_wT + j*CCH + c0);
      u32 uw[4]; *(bf16x8*)uw = wr;
      #pragma unroll
      for (int q = 0; q < 4; ++q) { wtv[j][2*q] = bflo(uw[q]); wtv[j][2*q+1] = bfhi(uw[q]); }
    }
    float s8[8] = {};
    #pragma unroll
    for (int kh = 0; kh < 3; ++kh) {
      int yy = h - 1 + kh;
      if (yy < 0 || yy >= HH) continue;
      #pragma unroll
      for (int kw = 0; kw < 3; ++kw) {
        int xx = w - 1 + kw;
        if (xx < 0 || xx >= WW) continue;
        bf16x8 raw = *(const bf16x8*)(src + (size_t)(yy*WW + xx)*CCH);
        u32 uw[4]; *(bf16x8*)uw = raw;
        #pragma unroll
        for (int q = 0; q < 4; ++q) {
          s8[2*q]   = fmaf(bflo(uw[q]), wtv[kh*3+kw][2*q],   s8[2*q]);
          s8[2*q+1] = fmaf(bfhi(uw[q]), wtv[kh*3+kw][2*q+1], s8[2*q+1]);
        }
      }
    }
    float4 db0 = *(const float4*)(dw_b + c0);
    float4 db1 = *(const float4*)(dw_b + c0 + 4);
    s8[0]+=db0.x; s8[1]+=db0.y; s8[2]+=db0.z; s8[3]+=db0.w;
    s8[4]+=db1.x; s8[5]+=db1.y; s8[6]+=db1.z; s8[7]+=db1.w;
    float s1 = 0.f, s2 = 0.f;
    #pragma unroll
    for (int j = 0; j < 8; ++j) { s1 += s8[j]; s2 += s8[j]*s8[j]; }
    #pragma unroll
    for (int m = 8; m >= 1; m >>= 1) {
      s1 += __shfl_xor(s1, m);
      s2 += __shfl_xor(s2, m);
    }
    float mean = s1 * (1.f/128.f);
    float var  = s2 * (1.f/128.f) - mean*mean;
    float rstd = rsqrtf(var + 1e-5f);
    float4 lg0 = *(const float4*)(ln_g + c0);
    float4 lg1 = *(const float4*)(ln_g + c0 + 4);
    float4 lb0 = *(const float4*)(ln_b + c0);
    float4 lb1 = *(const float4*)(ln_b + c0 + 4);
    float lg[8] = {lg0.x,lg0.y,lg0.z,lg0.w,lg1.x,lg1.y,lg1.z,lg1.w};
    float lb[8] = {lb0.x,lb0.y,lb0.z,lb0.w,lb1.x,lb1.y,lb1.z,lb1.w};
    u32 pk[4];
    #pragma unroll
    for (int q = 0; q < 4; ++q) {
      float v0 = (s8[2*q]   - mean) * rstd * lg[2*q]   + lb[2*q];
      float v1 = (s8[2*q+1] - mean) * rstd * lg[2*q+1] + lb[2*q+1];
      float g0 = 0.5f * v0 * (1.f + erff(v0 * 0.70710678f));
      float g1 = 0.5f * v1 * (1.f + erff(v1 * 0.70710678f));
      pk[q] = (u32)f2bf(g0) | ((u32)f2bf(g1) << 16);
    }
    *(bf16x8*)&x1t[px][c0] = *(bf16x8*)pk;
  }
  __syncthreads();

  // ---- phase 2: om heads via MFMA -> fbuf LDS (never HBM)
  {
    int wv = t >> 6, l = t & 63, c16 = l & 15, kq = l >> 4;
    int nt0 = wv*2;
    int ntn = (wv == 3) ? 1 : 2;
    f32x4 acc[2] = {};
    #pragma unroll
    for (int ks = 0; ks < 4; ++ks) {
      bf16x8 a = *(const bf16x8*)&x1t[c16][kq*8 + ks*32];
      #pragma unroll
      for (int j = 0; j < 2; ++j) {
        if (j < ntn) {
          bf16x8 b = *(const bf16x8*)(wTom + (size_t)((nt0+j)*16 + c16)*CCH + ks*32 + kq*8);
          acc[j] = __builtin_amdgcn_mfma_f32_16x16x32_bf16(a, b, acc[j], 0, 0, 0);
        }
      }
    }
    #pragma unroll
    for (int j = 0; j < 2; ++j) {
      if (j < ntn) {
        int c = (nt0+j)*16 + c16;
        float bs = (c < 72) ? b_off[c] : ((c < 108) ? b_mask[c - 72] : 0.f);
        #pragma unroll
        for (int r = 0; r < 4; ++r) {
          int px = kq*4 + r;
          if (c < 108) fbuf[px][c] = acc[j][r] + bs;
        }
      }
    }
  }
  __syncthreads();

  // ---- phase 3: softmax over mask logits (16 px x 4 groups = 64 tasks), in place
  if (t < 64) {
    int px = t >> 2, g = t & 3;
    float mx = -1e30f;
    #pragma unroll
    for (int q = 0; q < PP; ++q) mx = fmaxf(mx, fbuf[px][72 + g*PP + q]);
    float e[PP]; float sum = 0.f;
    #pragma unroll
    for (int q = 0; q < PP; ++q) { e[q] = __expf(fbuf[px][72 + g*PP + q] - mx); sum += e[q]; }
    float inv = 1.f / sum;
    #pragma unroll
    for (int q = 0; q < PP; ++q) fbuf[px][72 + g*PP + q] = e[q] * inv;
  }
  __syncthreads();

  // ---- phase 3.5: sampling precompute — 576 tasks = (px, g, p).
  //      Packs clamped corner indices (2x u16 per u32) + mask-premultiplied
  //      corner weights; kills the 16x-redundant coord math in phase 4.
  for (int i = t; i < 16*GG*PP; i += 256) {
    int px = i / (GG*PP);
    int r36 = i - px*(GG*PP);
    int g = r36 / PP;
    int p = r36 - g*PP;
    float offx = fbuf[px][(g*PP + p)*2 + 0];
    float offy = fbuf[px][(g*PP + p)*2 + 1];
    float mval = fbuf[px][72 + g*PP + p];
    int w = w0 + px;
    float ix = (float)w + 1.0f + (float)(p / 3 - 1) + offx;
    float iy = (float)h + 1.0f + (float)(p % 3 - 1) + offy;
    float x0f = floorf(ix), y0f = floorf(iy);
    float wx1 = ix - x0f, wx0 = 1.f - wx1;
    float wy1 = iy - y0f, wy0 = 1.f - wy1;
    int x0i = (int)x0f, y0i = (int)y0f;
    int ox0 = x0i - 1, oy0 = y0i - 1;   // padded -> original coords
    int ox1 = x0i,     oy1 = y0i;
    bool y0ok = (oy0 >= 0) & (oy0 < HH), y1ok = (oy1 >= 0) & (oy1 < HH);
    bool x0ok = (ox0 >= 0) & (ox0 < WW), x1ok = (ox1 >= 0) & (ox1 < WW);
    int cy0 = min(max(oy0, 0), HH-1), cy1 = min(max(oy1, 0), HH-1);
    int cx0 = min(max(ox0, 0), WW-1), cx1 = min(max(ox1, 0), WW-1);
    u32 i0 = (u32)(cy0*WW + cx0), i1 = (u32)(cy0*WW + cx1);
    u32 i2 = (u32)(cy1*WW + cx0), i3 = (u32)(cy1*WW + cx1);
    pinfo[i][0] = __builtin_bit_cast(float, i0 | (i1 << 16));
    pinfo[i][1] = __builtin_bit_cast(float, i2 | (i3 << 16));
    pinfo[i][2] = ((y0ok & x0ok) ? wy0*wx0 : 0.f) * mval;
    pinfo[i][3] = ((y0ok & x1ok) ? wy0*wx1 : 0.f) * mval;
    pinfo[i][4] = ((y1ok & x0ok) ? wy1*wx0 : 0.f) * mval;
    pinfo[i][5] = ((y1ok & x1ok) ? wy1*wx1 : 0.f) * mval;
  }
  __syncthreads();

  // ---- phase 4: bilinear sampling, 3-point batches (12 loads in flight)
  {
    int pxl = t >> 4, unit = t & 15;
    int g = unit >> 2, ch0 = unit * 8;
    const u16* basep = xpb + (size_t)n*SS*CCH + ch0;
    int pib = (pxl*GG + g)*PP;
    float a8[8] = {};
    #pragma unroll
    for (int bt = 0; bt < 3; ++bt) {
      bf16x8 raw[3][4];
      float wgt[3][4];
      #pragma unroll
      for (int q = 0; q < 3; ++q) {
        const float* pi = pinfo[pib + bt*3 + q];
        u32 i01 = __builtin_bit_cast(u32, pi[0]);
        u32 i23 = __builtin_bit_cast(u32, pi[1]);
        wgt[q][0] = pi[2]; wgt[q][1] = pi[3];
        wgt[q][2] = pi[4]; wgt[q][3] = pi[5];
        raw[q][0] = *(const bf16x8*)(basep + (size_t)(i01 & 0xffffu)*CCH);
        raw[q][1] = *(const bf16x8*)(basep + (size_t)(i01 >> 16)*CCH);
        raw[q][2] = *(const bf16x8*)(basep + (size_t)(i23 & 0xffffu)*CCH);
        raw[q][3] = *(const bf16x8*)(basep + (size_t)(i23 >> 16)*CCH);
      }
      #pragma unroll
      for (int q = 0; q < 3; ++q) {
        #pragma unroll
        for (int corner = 0; corner < 4; ++corner) {
          u32 uw[4]; *(bf16x8*)uw = raw[q][corner];
          float wg = wgt[q][corner];
          #pragma unroll
          for (int j = 0; j < 4; ++j) {
            a8[2*j]   = fmaf(wg, bflo(uw[j]), a8[2*j]);
            a8[2*j+1] = fmaf(wg, bfhi(uw[j]), a8[2*j+1]);
          }
        }
      }
    }
    u32 pk[4];
    #pragma unroll
    for (int j = 0; j < 4; ++j)
      pk[j] = (u32)f2bf(a8[2*j]) | ((u32)f2bf(a8[2*j+1]) << 16);
    *(bf16x8*)&dtile[pxl][ch0] = *(bf16x8*)pk;
  }
  __syncthreads();   // dtile ready; fbuf dead -> reusable as fout

  // ---- phase 5: out proj MFMA + BN + SiLU -> fbuf (as fout)
  {
    int wv = t >> 6, l = t & 63, c16 = l & 15, kq = l >> 4;
    f32x4 acc[2] = {};
    #pragma unroll
    for (int ks = 0; ks < 4; ++ks) {
      bf16x8 a = *(const bf16x8*)&dtile[c16][kq*8 + ks*32];
      #pragma unroll
      for (int j = 0; j < 2; ++j) {
        int nt = wv*2 + j;
        bf16x8 b = *(const bf16x8*)(wTout + (size_t)(nt*16 + c16)*CCH + ks*32 + kq*8);
        acc[j] = __builtin_amdgcn_mfma_f32_16x16x32_bf16(a, b, acc[j], 0, 0, 0);
      }
    }
    #pragma unroll
    for (int j = 0; j < 2; ++j) {
      int c = (wv*2 + j)*16 + c16;
      float sc = rsqrtf(bn_var[c] + 1e-5f) * bn_g[c];
      float sh = bn_b[c] - bn_mean[c] * sc;
      float bs = b_out[c];
      #pragma unroll
      for (int r = 0; r < 4; ++r) {
        int px = kq*4 + r;
        float v = (acc[j][r] + bs) * sc + sh;
        float sig = 1.f / (1.f + __expf(-v));
        fbuf[px][c] = v * sig;
      }
    }
  }
  __syncthreads();

  // ---- phase 6: NCHW store (float4 along pixels; 128c x 4 quads = 512 tasks)
  {
    float* dst = y + ((size_t)n*CCH)*SS + (size_t)h*WW + w0;
    #pragma unroll
    for (int i = 0; i < 2; ++i) {
      int id = t + i*256;
      int c = id >> 2, p4 = (id & 3) * 4;
      float4 v = { fbuf[p4][c], fbuf[p4+1][c], fbuf[p4+2][c], fbuf[p4+3][c] };
      *(float4*)(dst + (size_t)c*SS + p4) = v;
    }
  }
}

extern "C" void kernel_launch(void* const* d_in, const int* in_sizes, int n_in,
                              void* d_out, int out_size, void* d_ws, size_t ws_size,
                              hipStream_t stream) {
  const float* x       = (const float*)d_in[0];
  const float* dw_w    = (const float*)d_in[1];
  const float* dw_b    = (const float*)d_in[2];
  const float* ln_g    = (const float*)d_in[3];
  const float* ln_b    = (const float*)d_in[4];
  const float* w_off   = (const float*)d_in[5];
  const float* b_off   = (const float*)d_in[6];
  const float* w_mask  = (const float*)d_in[7];
  const float* b_mask  = (const float*)d_in[8];
  const float* w_in    = (const float*)d_in[9];
  const float* b_in    = (const float*)d_in[10];
  const float* w_out   = (const float*)d_in[11];
  const float* b_out   = (const float*)d_in[12];
  const float* bn_g    = (const float*)d_in[13];
  const float* bn_b    = (const float*)d_in[14];
  const float* bn_mean = (const float*)d_in[15];
  const float* bn_var  = (const float*)d_in[16];
  float* y = (float*)d_out;

  u16*  xTb  = (u16*)d_ws;                        // NPIX*128 bf16
  u16*  xpb  = xTb + (size_t)NPIX*CCH;            // NPIX*128 bf16
  u16*  wbuf = xpb + (size_t)NPIX*CCH;
  u16*  w_inT  = wbuf;                            // 128*128
  u16*  w_omT  = w_inT + 128*128;                 // 112*128
  u16*  w_outT = w_omT + 112*128;                 // 128*128
  u16*  dw_wTb = w_outT + 128*128;                // 9*128

  k_prep<<<377, 128, 0, stream>>>(w_in, w_off, w_mask, w_out, dw_w,
                                  w_inT, w_omT, w_outT, dw_wTb);
  k_trproj<<<NPIX/32, 256, 0, stream>>>(x, w_inT, b_in, xTb, xpb);
  k_dwomdcn<<<NPIX/16, 256, 0, stream>>>(xTb, xpb, dw_wTb, dw_b, ln_g, ln_b,
                                         w_omT, b_off, b_mask,
                                         w_outT, b_out,
                                         bn_g, bn_b, bn_mean, bn_var, y);
}

// Round 13
// 161.307 us; speedup vs baseline: 1.0856x; 1.0006x over previous
//
#include <hip/hip_runtime.h>
#include <math.h>

#define NN 4
#define CCH 128
#define HH 96
#define WW 96
#define SS (HH*WW)          // 9216
#define GG 4
#define GC 32
#define PP 9
#define NPIX (NN*HH*WW)     // 36864

typedef _Float16 f16;
typedef _Float16 f16x2 __attribute__((ext_vector_type(2)));
typedef _Float16 f16x8 __attribute__((ext_vector_type(8)));
typedef float f32x4 __attribute__((ext_vector_type(4)));
typedef unsigned short u16;
typedef unsigned int u32;

static __device__ __forceinline__ f16x2 h2(u32 u) {
  return __builtin_bit_cast(f16x2, u);
}
static __device__ __forceinline__ u32 pkrtz(float a, float b) {
  return __builtin_bit_cast(u32, __builtin_amdgcn_cvt_pkrtz(a, b));
}

// ---------------- prep: transpose + f16-convert weights (+ dw conv weights)
__global__ __launch_bounds__(128) void k_prep(const float* __restrict__ w_in,
    const float* __restrict__ w_off, const float* __restrict__ w_mask,
    const float* __restrict__ w_out, const float* __restrict__ dw_w,
    f16* __restrict__ w_inT, f16* __restrict__ w_omT, f16* __restrict__ w_outT,
    f16* __restrict__ dw_wT) {
  int r = blockIdx.x, k = threadIdx.x;
  if (r < 128) {
    w_inT[r*128 + k] = (f16)w_in[k*128 + r];
  } else if (r < 240) {
    int c = r - 128;
    float v = 0.f;
    if (c < 72) v = w_off[k*72 + c];
    else if (c < 108) v = w_mask[k*36 + (c - 72)];
    w_omT[c*128 + k] = (f16)v;
  } else if (r < 368) {
    int c = r - 240;
    w_outT[c*128 + k] = (f16)w_out[k*128 + c];
  } else {
    int j = r - 368;                      // 0..8
    dw_wT[j*128 + k] = (f16)dw_w[k*9 + j];
  }
}

// ---------------- fused transpose + input projection (32 px/block, 256 thr)
__global__ __launch_bounds__(256) void k_trproj(const float* __restrict__ x,
    const f16* __restrict__ wT, const float* __restrict__ bias,
    f16* __restrict__ xTb, f16* __restrict__ xpb) {
  __shared__ f16 tile[32][136];
  int t = threadIdx.x;
  int pb = blockIdx.x * 32;             // same n (9216%32==0)
  int n = pb / SS, ps = pb % SS;
  const float* src = x + ((size_t)n*CCH)*SS + ps;

  // ---- phase L: 128 c-rows x 8 float4 = 1024 tasks
  #pragma unroll
  for (int i = 0; i < 4; ++i) {
    int fid = t + i*256;
    int c = fid >> 3, q = fid & 7;
    float4 v = *(const float4*)(src + (size_t)c*SS + q*4);
    int px = q*4;
    tile[px+0][c] = (f16)v.x;
    tile[px+1][c] = (f16)v.y;
    tile[px+2][c] = (f16)v.z;
    tile[px+3][c] = (f16)v.w;
  }
  __syncthreads();

  // ---- phase M1: coalesced xTb store (32px x 64 u32 = 2048 tasks)
  {
    u32* dst = (u32*)(xTb + (size_t)pb*CCH);
    #pragma unroll
    for (int i = 0; i < 8; ++i) {
      int gidx = t + i*256;
      int px = gidx >> 6, cp = gidx & 63;
      dst[(size_t)px*64 + cp] = *(const u32*)&tile[px][cp*2];
    }
  }

  // ---- phase M2: MFMA proj. wave w: px half (w&1)*16, nt quarter (w>>1)*4
  {
    int wv = t >> 6, l = t & 63, c16 = l & 15, kq = l >> 4;
    int pxl0 = (wv & 1) * 16;
    int nt0 = (wv >> 1) * 4;
    f16x8 a[4];
    #pragma unroll
    for (int ks = 0; ks < 4; ++ks)
      a[ks] = *(const f16x8*)&tile[pxl0 + c16][kq*8 + ks*32];
    f32x4 acc[4] = {};
    #pragma unroll
    for (int ks = 0; ks < 4; ++ks) {
      #pragma unroll
      for (int j = 0; j < 4; ++j) {
        f16x8 b = *(const f16x8*)(wT + (size_t)((nt0+j)*16 + c16)*CCH + ks*32 + kq*8);
        acc[j] = __builtin_amdgcn_mfma_f32_16x16x32_f16(a[ks], b, acc[j], 0, 0, 0);
      }
    }
    #pragma unroll
    for (int j = 0; j < 4; ++j) {
      int c = (nt0+j)*16 + c16;
      float bs = bias[c];
      #pragma unroll
      for (int r = 0; r < 4; ++r)
        xpb[(size_t)(pb + pxl0 + kq*4 + r)*CCH + c] = (f16)(acc[j][r] + bs);
    }
  }
}

// ---------------- MEGA: dwconv3x3+LN+GELU -> om heads (MFMA) -> softmax
//                  -> sample-precompute -> DCN sampling (pk_fma_f16)
//                  -> out proj (MFMA) -> BN+SiLU -> NCHW.
//                  16 px/block, 256 threads, 7 barriers.
__global__ __launch_bounds__(256) void k_dwomdcn(const f16* __restrict__ xTb,
    const f16* __restrict__ xpb,
    const f16* __restrict__ dw_wT, const float* __restrict__ dw_b,
    const float* __restrict__ ln_g, const float* __restrict__ ln_b,
    const f16* __restrict__ wTom, const float* __restrict__ b_off,
    const float* __restrict__ b_mask,
    const f16* __restrict__ wTout, const float* __restrict__ b_out,
    const float* __restrict__ bn_g, const float* __restrict__ bn_b,
    const float* __restrict__ bn_mean, const float* __restrict__ bn_var,
    float* __restrict__ y) {
  __shared__ f16 x1t[16][136];         // GELU(LN(conv)) f16
  __shared__ f16 dtile[16][136];       // dcn result f16
  __shared__ float fbuf[16][132];      // cols 0..71 offs, 72..107 mask; later fout
  __shared__ float pinfo[16*GG*PP][4]; // per (px,g,p): idx01, idx23, w01(f16x2), w23(f16x2)
  int t = threadIdx.x;
  int blk = blockIdx.x;
  const int W16 = WW/16;                        // 6
  int w0 = (blk % W16) * 16;
  int h  = (blk / W16) % HH;
  int n  = blk / (W16*HH);

  // ---- phase 1: conv (pk_fma_f16) + LN + GELU (thread = px x 8-ch group)
  {
    int px = t >> 4, cg = t & 15;
    int w = w0 + px;
    int c0 = cg * 8;
    const f16* src = xTb + (size_t)n*SS*CCH + c0;
    uint4 wr[9];
    #pragma unroll
    for (int j = 0; j < 9; ++j) wr[j] = *(const uint4*)(dw_wT + j*CCH + c0);
    f16x2 sacc[4] = {};
    #pragma unroll
    for (int kh = 0; kh < 3; ++kh) {
      int yy = h - 1 + kh;
      if (yy < 0 || yy >= HH) continue;
      #pragma unroll
      for (int kw = 0; kw < 3; ++kw) {
        int xx = w - 1 + kw;
        if (xx < 0 || xx >= WW) continue;
        uint4 raw = *(const uint4*)(src + (size_t)(yy*WW + xx)*CCH);
        const uint4& wj = wr[kh*3 + kw];
        sacc[0] += h2(raw.x) * h2(wj.x);
        sacc[1] += h2(raw.y) * h2(wj.y);
        sacc[2] += h2(raw.z) * h2(wj.z);
        sacc[3] += h2(raw.w) * h2(wj.w);
      }
    }
    float s8[8];
    #pragma unroll
    for (int q = 0; q < 4; ++q) {
      s8[2*q]   = (float)sacc[q].x;
      s8[2*q+1] = (float)sacc[q].y;
    }
    float4 db0 = *(const float4*)(dw_b + c0);
    float4 db1 = *(const float4*)(dw_b + c0 + 4);
    s8[0]+=db0.x; s8[1]+=db0.y; s8[2]+=db0.z; s8[3]+=db0.w;
    s8[4]+=db1.x; s8[5]+=db1.y; s8[6]+=db1.z; s8[7]+=db1.w;
    float s1 = 0.f, s2 = 0.f;
    #pragma unroll
    for (int j = 0; j < 8; ++j) { s1 += s8[j]; s2 += s8[j]*s8[j]; }
    #pragma unroll
    for (int m = 8; m >= 1; m >>= 1) {
      s1 += __shfl_xor(s1, m);
      s2 += __shfl_xor(s2, m);
    }
    float mean = s1 * (1.f/128.f);
    float var  = s2 * (1.f/128.f) - mean*mean;
    float rstd = rsqrtf(var + 1e-5f);
    float4 lg0 = *(const float4*)(ln_g + c0);
    float4 lg1 = *(const float4*)(ln_g + c0 + 4);
    float4 lb0 = *(const float4*)(ln_b + c0);
    float4 lb1 = *(const float4*)(ln_b + c0 + 4);
    float lg[8] = {lg0.x,lg0.y,lg0.z,lg0.w,lg1.x,lg1.y,lg1.z,lg1.w};
    float lb[8] = {lb0.x,lb0.y,lb0.z,lb0.w,lb1.x,lb1.y,lb1.z,lb1.w};
    u32 pk[4];
    #pragma unroll
    for (int q = 0; q < 4; ++q) {
      float v0 = (s8[2*q]   - mean) * rstd * lg[2*q]   + lb[2*q];
      float v1 = (s8[2*q+1] - mean) * rstd * lg[2*q+1] + lb[2*q+1];
      float g0 = 0.5f * v0 * (1.f + erff(v0 * 0.70710678f));
      float g1 = 0.5f * v1 * (1.f + erff(v1 * 0.70710678f));
      pk[q] = pkrtz(g0, g1);
    }
    *(uint4*)&x1t[px][c0] = *(uint4*)pk;
  }
  __syncthreads();

  // ---- phase 2: om heads via MFMA -> fbuf LDS (never HBM)
  {
    int wv = t >> 6, l = t & 63, c16 = l & 15, kq = l >> 4;
    int nt0 = wv*2;
    int ntn = (wv == 3) ? 1 : 2;
    f32x4 acc[2] = {};
    #pragma unroll
    for (int ks = 0; ks < 4; ++ks) {
      f16x8 a = *(const f16x8*)&x1t[c16][kq*8 + ks*32];
      #pragma unroll
      for (int j = 0; j < 2; ++j) {
        if (j < ntn) {
          f16x8 b = *(const f16x8*)(wTom + (size_t)((nt0+j)*16 + c16)*CCH + ks*32 + kq*8);
          acc[j] = __builtin_amdgcn_mfma_f32_16x16x32_f16(a, b, acc[j], 0, 0, 0);
        }
      }
    }
    #pragma unroll
    for (int j = 0; j < 2; ++j) {
      if (j < ntn) {
        int c = (nt0+j)*16 + c16;
        float bs = (c < 72) ? b_off[c] : ((c < 108) ? b_mask[c - 72] : 0.f);
        #pragma unroll
        for (int r = 0; r < 4; ++r) {
          int px = kq*4 + r;
          if (c < 108) fbuf[px][c] = acc[j][r] + bs;
        }
      }
    }
  }
  __syncthreads();

  // ---- phase 3: softmax over mask logits (16 px x 4 groups = 64 tasks), in place
  if (t < 64) {
    int px = t >> 2, g = t & 3;
    float mx = -1e30f;
    #pragma unroll
    for (int q = 0; q < PP; ++q) mx = fmaxf(mx, fbuf[px][72 + g*PP + q]);
    float e[PP]; float sum = 0.f;
    #pragma unroll
    for (int q = 0; q < PP; ++q) { e[q] = __expf(fbuf[px][72 + g*PP + q] - mx); sum += e[q]; }
    float inv = 1.f / sum;
    #pragma unroll
    for (int q = 0; q < PP; ++q) fbuf[px][72 + g*PP + q] = e[q] * inv;
  }
  __syncthreads();

  // ---- phase 3.5: sampling precompute — 576 tasks = (px, g, p).
  //      Clamped corner indices (2x u16 per u32) + mask-premultiplied
  //      corner weights packed as f16x2 pairs.
  for (int i = t; i < 16*GG*PP; i += 256) {
    int px = i / (GG*PP);
    int r36 = i - px*(GG*PP);
    int g = r36 / PP;
    int p = r36 - g*PP;
    float offx = fbuf[px][(g*PP + p)*2 + 0];
    float offy = fbuf[px][(g*PP + p)*2 + 1];
    float mval = fbuf[px][72 + g*PP + p];
    int w = w0 + px;
    float ix = (float)w + 1.0f + (float)(p / 3 - 1) + offx;
    float iy = (float)h + 1.0f + (float)(p % 3 - 1) + offy;
    float x0f = floorf(ix), y0f = floorf(iy);
    float wx1 = ix - x0f, wx0 = 1.f - wx1;
    float wy1 = iy - y0f, wy0 = 1.f - wy1;
    int x0i = (int)x0f, y0i = (int)y0f;
    int ox0 = x0i - 1, oy0 = y0i - 1;   // padded -> original coords
    int ox1 = x0i,     oy1 = y0i;
    bool y0ok = (oy0 >= 0) & (oy0 < HH), y1ok = (oy1 >= 0) & (oy1 < HH);
    bool x0ok = (ox0 >= 0) & (ox0 < WW), x1ok = (ox1 >= 0) & (ox1 < WW);
    int cy0 = min(max(oy0, 0), HH-1), cy1 = min(max(oy1, 0), HH-1);
    int cx0 = min(max(ox0, 0), WW-1), cx1 = min(max(ox1, 0), WW-1);
    u32 i0 = (u32)(cy0*WW + cx0), i1 = (u32)(cy0*WW + cx1);
    u32 i2 = (u32)(cy1*WW + cx0), i3 = (u32)(cy1*WW + cx1);
    float w00 = ((y0ok & x0ok) ? wy0*wx0 : 0.f) * mval;
    float w01 = ((y0ok & x1ok) ? wy0*wx1 : 0.f) * mval;
    float w10 = ((y1ok & x0ok) ? wy1*wx0 : 0.f) * mval;
    float w11 = ((y1ok & x1ok) ? wy1*wx1 : 0.f) * mval;
    pinfo[i][0] = __builtin_bit_cast(float, i0 | (i1 << 16));
    pinfo[i][1] = __builtin_bit_cast(float, i2 | (i3 << 16));
    pinfo[i][2] = __builtin_bit_cast(float, pkrtz(w00, w01));
    pinfo[i][3] = __builtin_bit_cast(float, pkrtz(w10, w11));
  }
  __syncthreads();

  // ---- phase 4: bilinear sampling via pk_fma_f16, 3-point batches
  {
    int pxl = t >> 4, unit = t & 15;
    int g = unit >> 2, ch0 = unit * 8;
    const f16* basep = xpb + (size_t)n*SS*CCH + ch0;
    int pib = (pxl*GG + g)*PP;
    float a8[8] = {};
    #pragma unroll
    for (int bt = 0; bt < 3; ++bt) {
      uint4 raw[3][4];
      f16x2 wgt[3][2];
      #pragma unroll
      for (int q = 0; q < 3; ++q) {
        const float* pi = pinfo[pib + bt*3 + q];
        u32 i01 = __builtin_bit_cast(u32, pi[0]);
        u32 i23 = __builtin_bit_cast(u32, pi[1]);
        wgt[q][0] = __builtin_bit_cast(f16x2, pi[2]);
        wgt[q][1] = __builtin_bit_cast(f16x2, pi[3]);
        raw[q][0] = *(const uint4*)(basep + (size_t)(i01 & 0xffffu)*CCH);
        raw[q][1] = *(const uint4*)(basep + (size_t)(i01 >> 16)*CCH);
        raw[q][2] = *(const uint4*)(basep + (size_t)(i23 & 0xffffu)*CCH);
        raw[q][3] = *(const uint4*)(basep + (size_t)(i23 >> 16)*CCH);
      }
      #pragma unroll
      for (int q = 0; q < 3; ++q) {
        f16x2 v[4] = {};
        #pragma unroll
        for (int c = 0; c < 4; ++c) {
          f16 wsc = (c & 1) ? wgt[q][c>>1].y : wgt[q][c>>1].x;
          f16x2 ws = {wsc, wsc};
          v[0] += h2(raw[q][c].x) * ws;
          v[1] += h2(raw[q][c].y) * ws;
          v[2] += h2(raw[q][c].z) * ws;
          v[3] += h2(raw[q][c].w) * ws;
        }
        #pragma unroll
        for (int j = 0; j < 4; ++j) {
          a8[2*j]   += (float)v[j].x;
          a8[2*j+1] += (float)v[j].y;
        }
      }
    }
    uint4 pk;
    pk.x = pkrtz(a8[0], a8[1]);
    pk.y = pkrtz(a8[2], a8[3]);
    pk.z = pkrtz(a8[4], a8[5]);
    pk.w = pkrtz(a8[6], a8[7]);
    *(uint4*)&dtile[pxl][ch0] = pk;
  }
  __syncthreads();   // dtile ready; fbuf dead -> reusable as fout

  // ---- phase 5: out proj MFMA + BN + SiLU -> fbuf (as fout)
  {
    int wv = t >> 6, l = t & 63, c16 = l & 15, kq = l >> 4;
    f32x4 acc[2] = {};
    #pragma unroll
    for (int ks = 0; ks < 4; ++ks) {
      f16x8 a = *(const f16x8*)&dtile[c16][kq*8 + ks*32];
      #pragma unroll
      for (int j = 0; j < 2; ++j) {
        int nt = wv*2 + j;
        f16x8 b = *(const f16x8*)(wTout + (size_t)(nt*16 + c16)*CCH + ks*32 + kq*8);
        acc[j] = __builtin_amdgcn_mfma_f32_16x16x32_f16(a, b, acc[j], 0, 0, 0);
      }
    }
    #pragma unroll
    for (int j = 0; j < 2; ++j) {
      int c = (wv*2 + j)*16 + c16;
      float sc = rsqrtf(bn_var[c] + 1e-5f) * bn_g[c];
      float sh = bn_b[c] - bn_mean[c] * sc;
      float bs = b_out[c];
      #pragma unroll
      for (int r = 0; r < 4; ++r) {
        int px = kq*4 + r;
        float v = (acc[j][r] + bs) * sc + sh;
        float sig = 1.f / (1.f + __expf(-v));
        fbuf[px][c] = v * sig;
      }
    }
  }
  __syncthreads();

  // ---- phase 6: NCHW store (float4 along pixels; 128c x 4 quads = 512 tasks)
  {
    float* dst = y + ((size_t)n*CCH)*SS + (size_t)h*WW + w0;
    #pragma unroll
    for (int i = 0; i < 2; ++i) {
      int id = t + i*256;
      int c = id >> 2, p4 = (id & 3) * 4;
      float4 v = { fbuf[p4][c], fbuf[p4+1][c], fbuf[p4+2][c], fbuf[p4+3][c] };
      *(float4*)(dst + (size_t)c*SS + p4) = v;
    }
  }
}

extern "C" void kernel_launch(void* const* d_in, const int* in_sizes, int n_in,
                              void* d_out, int out_size, void* d_ws, size_t ws_size,
                              hipStream_t stream) {
  const float* x       = (const float*)d_in[0];
  const float* dw_w    = (const float*)d_in[1];
  const float* dw_b    = (const float*)d_in[2];
  const float* ln_g    = (const float*)d_in[3];
  const float* ln_b    = (const float*)d_in[4];
  const float* w_off   = (const float*)d_in[5];
  const float* b_off   = (const float*)d_in[6];
  const float* w_mask  = (const float*)d_in[7];
  const float* b_mask  = (const float*)d_in[8];
  const float* w_in    = (const float*)d_in[9];
  const float* b_in    = (const float*)d_in[10];
  const float* w_out   = (const float*)d_in[11];
  const float* b_out   = (const float*)d_in[12];
  const float* bn_g    = (const float*)d_in[13];
  const float* bn_b    = (const float*)d_in[14];
  const float* bn_mean = (const float*)d_in[15];
  const float* bn_var  = (const float*)d_in[16];
  float* y = (float*)d_out;

  f16*  xTb  = (f16*)d_ws;                        // NPIX*128 f16
  f16*  xpb  = xTb + (size_t)NPIX*CCH;            // NPIX*128 f16
  f16*  wbuf = xpb + (size_t)NPIX*CCH;
  f16*  w_inT  = wbuf;                            // 128*128
  f16*  w_omT  = w_inT + 128*128;                 // 112*128
  f16*  w_outT = w_omT + 112*128;                 // 128*128
  f16*  dw_wTb = w_outT + 128*128;                // 9*128

  k_prep<<<377, 128, 0, stream>>>(w_in, w_off, w_mask, w_out, dw_w,
                                  w_inT, w_omT, w_outT, dw_wTb);
  k_trproj<<<NPIX/32, 256, 0, stream>>>(x, w_inT, b_in, xTb, xpb);
  k_dwomdcn<<<NPIX/16, 256, 0, stream>>>(xTb, xpb, dw_wTb, dw_b, ln_g, ln_b,
                                         w_omT, b_off, b_mask,
                                         w_outT, b_out,
                                         bn_g, bn_b, bn_mean, bn_var, y);
}